// Round 3
// baseline (115.620 us; speedup 1.0000x reference)
//
#include <hip/hip_runtime.h>
#include <stdint.h>

#define LSEQ 256
#define EMB  256
#define K3F  768
#define SCOFF (4 * 256 * 256 * 6)

typedef short bf16x8 __attribute__((ext_vector_type(8)));
typedef float f32x4  __attribute__((ext_vector_type(4)));

__device__ __forceinline__ uint16_t f2bf(float x) {
    union { float f; uint32_t u; } c; c.f = x;
    uint32_t r = c.u + 0x7fffu + ((c.u >> 16) & 1u);
    return (uint16_t)(r >> 16);
}

// scale a packed pair of bf16 (in one u32) by two f32 weights, repack bf16
__device__ __forceinline__ uint32_t scale_pk(uint32_t u, float t0, float t1) {
    union { uint32_t u; float f; } lo, hi;
    lo.u = u << 16;
    hi.u = u & 0xffff0000u;
    float a = lo.f * t0;
    float b = hi.f * t1;
    return (uint32_t)f2bf(a) | ((uint32_t)f2bf(b) << 16);
}

// ---------- prep: gather->embB bf16 (rows 4+l, zero halo), wprep->Wt[t][c][i] bf16
// grid 804 = 32 gather + 4 pad + 768 wprep (one thread per (c,i), K loads/stores)
__global__ __launch_bounds__(256) void k_prep(const int* __restrict__ ids,
                                              const float* __restrict__ table,
                                              const float* __restrict__ w2,
                                              const float* __restrict__ w3,
                                              const float* __restrict__ w4,
                                              uint16_t* __restrict__ embB,
                                              uint16_t* __restrict__ Wt2,
                                              uint16_t* __restrict__ Wt3,
                                              uint16_t* __restrict__ Wt4) {
    int blk = blockIdx.x, tid = threadIdx.x;
    if (blk < 32) {                       // gather: 4b x 8 l-chunks of 32
        int b = blk >> 3, l0 = (blk & 7) << 5;
        int r = tid >> 3, p = tid & 7;
        int id = ids[(b << 8) + l0 + r];
        const float* src = table + (size_t)id * EMB + p * 32;
        uint16_t* dst = embB + (size_t)(b * 272 + 4 + l0 + r) * 256 + p * 32;
#pragma unroll
        for (int s = 0; s < 8; ++s) {
            float4 v = *(const float4*)(src + 4 * s);
            uint32_t lo = f2bf(v.x) | ((uint32_t)f2bf(v.y) << 16);
            uint32_t hi = f2bf(v.z) | ((uint32_t)f2bf(v.w) << 16);
            *(uint2*)(dst + 4 * s) = make_uint2(lo, hi);
        }
    } else if (blk < 36) {                // zero pad rows 0..3, 260..271
        int b = blk - 32;
        int ri = tid >> 4;
        int row = ri < 4 ? ri : 256 + ri;
        int off = (tid & 15) * 16;
        uint16_t* dst = embB + (size_t)(b * 272 + row) * 256 + off;
        *(uint4*)dst = make_uint4(0, 0, 0, 0);
        *(uint4*)(dst + 8) = make_uint4(0, 0, 0, 0);
    } else {                              // wprep: thread = (c,i), 65536 per group
        int n = (blk - 36) * 256 + tid;
        if (n < 65536) {
            int c = n >> 8, i = n & 255;
            float2 v = *(const float2*)(w2 + (c << 9) + (i << 1));
            Wt2[c * 256 + i]         = f2bf(v.x);
            Wt2[65536 + c * 256 + i] = f2bf(v.y);
        } else if (n < 131072) {
            int m = n - 65536;
            int c = m >> 8, i = m & 255;
            const float* s = w3 + c * 768 + i * 3;
#pragma unroll
            for (int t = 0; t < 3; ++t)
                Wt3[t * 65536 + c * 256 + i] = f2bf(s[t]);
        } else {
            int m = n - 131072;
            int c = m >> 8, i = m & 255;
            float4 v = *(const float4*)(w4 + (c << 10) + (i << 2));
            Wt4[c * 256 + i]              = f2bf(v.x);
            Wt4[65536 + c * 256 + i]      = f2bf(v.y);
            Wt4[2 * 65536 + c * 256 + i]  = f2bf(v.z);
            Wt4[3 * 65536 + c * 256 + i]  = f2bf(v.w);
        }
    }
}

// ---------- conv as MFMA GEMM, 32c x 32l tiles, i-chunk 64 (R1 proven form)
template <int K, int PAD>
__device__ __forceinline__ void convg_body(const uint16_t* __restrict__ Wt,
                                           const float* __restrict__ bias,
                                           const uint16_t* __restrict__ embB,
                                           uint16_t* __restrict__ VB,
                                           int b, int c0, int l0, int gbase,
                                           uint16_t (*As)[32][72], uint16_t (*Bs)[72]) {
    const int tid = threadIdx.x;
    const int lane = tid & 63, wave = tid >> 6;
    const int ms = wave >> 1, ns = wave & 1;
    const int m = lane & 15, q = lane >> 4;
    const int ar = tid >> 3, aseg = (tid & 7) * 8;

    const uint16_t* wsrc  = Wt + (size_t)(c0 + ar) * 256 + aseg;                       // +t*65536 + i0
    const uint16_t* bsrc  = embB + (size_t)(b * 272 + 3 + l0 + ar) * 256 + aseg;       // +i0
    const int r2 = 32 + (tid >> 3);
    const uint16_t* bsrc2 = embB + (size_t)(b * 272 + 3 + l0 + r2) * 256 + aseg;       // tid<32 only

    bf16x8 ra[K], rb, rb2;
#pragma unroll
    for (int t = 0; t < K; ++t) ra[t] = *(const bf16x8*)(wsrc + t * 65536);
    rb = *(const bf16x8*)bsrc;
    if (tid < 32) rb2 = *(const bf16x8*)bsrc2;

    f32x4 acc;
#pragma unroll
    for (int z = 0; z < 4; ++z) acc[z] = 0.f;

#pragma unroll
    for (int i0 = 0; i0 < EMB; i0 += 64) {
        __syncthreads();
#pragma unroll
        for (int t = 0; t < K; ++t) *(bf16x8*)&As[t][ar][aseg] = ra[t];
        *(bf16x8*)&Bs[ar][aseg] = rb;
        if (tid < 32) *(bf16x8*)&Bs[r2][aseg] = rb2;
        __syncthreads();
        if (i0 + 64 < EMB) {            // prefetch next i-chunk; latency hides under MFMA
#pragma unroll
            for (int t = 0; t < K; ++t) ra[t] = *(const bf16x8*)(wsrc + t * 65536 + i0 + 64);
            rb = *(const bf16x8*)(bsrc + i0 + 64);
            if (tid < 32) rb2 = *(const bf16x8*)(bsrc2 + i0 + 64);
        }
#pragma unroll
        for (int t = 0; t < K; ++t) {
#pragma unroll
            for (int kh = 0; kh < 64; kh += 32) {
                bf16x8 afr = *(const bf16x8*)&As[t][ms * 16 + m][kh + q * 8];
                bf16x8 bfr = *(const bf16x8*)&Bs[ns * 16 + m + t - PAD + 1][kh + q * 8];
                acc = __builtin_amdgcn_mfma_f32_16x16x32_bf16(afr, bfr, acc, 0, 0, 0);
            }
        }
    }
    __syncthreads();
    float (*Cs)[36] = (float(*)[36])As;   // 4,608 B reuse
#pragma unroll
    for (int rg = 0; rg < 4; ++rg)
        Cs[ms * 16 + q * 4 + rg][ns * 16 + m] = acc[rg];
    __syncthreads();
    const int l = tid >> 3, cs = (tid & 7) * 4;
    const float4 bv = *(const float4*)(bias + c0 + cs);
    union { uint16_t h[4]; uint32_t d[2]; } pk;
    pk.h[0] = f2bf(Cs[cs + 0][l] + bv.x);
    pk.h[1] = f2bf(Cs[cs + 1][l] + bv.y);
    pk.h[2] = f2bf(Cs[cs + 2][l] + bv.z);
    pk.h[3] = f2bf(Cs[cs + 3][l] + bv.w);
    uint16_t* vdst = VB + (size_t)(b * 256 + l0 + l) * K3F + gbase + c0 + cs;
    *(uint2*)vdst = make_uint2(pk.d[0], pk.d[1]);
}

__global__ __launch_bounds__(256, 4) void k_convg(const uint16_t* __restrict__ Wt2,
                                                  const uint16_t* __restrict__ Wt3,
                                                  const uint16_t* __restrict__ Wt4,
                                                  const float* __restrict__ b2,
                                                  const float* __restrict__ b3,
                                                  const float* __restrict__ b4,
                                                  const uint16_t* __restrict__ embB,
                                                  uint16_t* __restrict__ VB) {
    __shared__ __align__(16) uint16_t As[4][32][72];
    __shared__ __align__(16) uint16_t Bs[36][72];
    int blk = blockIdx.x;                 // 768 = 4b * 3g * 8c0 * 8l0
    int b = blk & 3, rest = blk >> 2;
    int g = rest >> 6, rr = rest & 63;
    int c0 = (rr >> 3) * 32, l0 = (rr & 7) * 32;
    if (g == 0)      convg_body<2, 0>(Wt2, b2, embB, VB, b, c0, l0, 0,   As, Bs);
    else if (g == 1) convg_body<3, 1>(Wt3, b3, embB, VB, b, c0, l0, 256, As, Bs);
    else             convg_body<4, 1>(Wt4, b4, embB, VB, b, c0, l0, 512, As, Bs);
}

// ---------- pair GEMM v3: 64i x 64j tiles, 2x2 MFMA outer product per wave
// grid 448 = 4b * 4it * 4jp * 7c (c-stride 64 % 8 == 0 -> same XCD, VB rows L2-local)
// tw_c scale factors register-prefetched from global (L1-hot); A scaled at LDS-write.
__global__ __launch_bounds__(256, 4) void k_pairc3(const uint16_t* __restrict__ VB,
                                                   const float* __restrict__ tw,
                                                   const float* __restrict__ sw,
                                                   const float* __restrict__ tb,
                                                   const float* __restrict__ sb,
                                                   float* __restrict__ dout) {
    __shared__ __align__(16) uint16_t T[128][136]; // rows 0..63 = scaled A(i), 64..127 = B(j)
    int blk = blockIdx.x;
    int b = blk & 3, r = blk >> 2;
    int it = r & 3; r >>= 2;
    int jp = r & 3; int c = r >> 2;       // c in 0..6
    int i0 = it * 64, j0 = jp * 64;
    int tid = threadIdx.x;

    int lane = tid & 63, wave = tid >> 6;
    int iw = (wave >> 1) * 32, jw = (wave & 1) * 32;
    int m = lane & 15, q = lane >> 4;
    int ar = tid >> 2, aseg = (tid & 3) * 32;   // stage: 64 rows x 4 thr/row x 32 halfs

    const uint16_t* srcA = VB + (size_t)(b * 256 + i0 + ar) * K3F + aseg;
    const uint16_t* srcB = VB + (size_t)(b * 256 + j0 + ar) * K3F + aseg;
    const float*    srcT = ((c < 6) ? (tw + c * K3F) : sw) + aseg;

    bf16x8 rA[4], rB[4];
    float4 rT[8];
#pragma unroll
    for (int p = 0; p < 4; ++p) {
        rA[p] = *(const bf16x8*)(srcA + p * 8);
        rB[p] = *(const bf16x8*)(srcB + p * 8);
        rT[2 * p]     = *(const float4*)(srcT + p * 8);
        rT[2 * p + 1] = *(const float4*)(srcT + p * 8 + 4);
    }

    f32x4 acc[2][2];
#pragma unroll
    for (int a = 0; a < 2; ++a)
#pragma unroll
        for (int n = 0; n < 2; ++n)
#pragma unroll
            for (int z = 0; z < 4; ++z) acc[a][n][z] = 0.f;

#pragma unroll
    for (int kc = 0; kc < K3F; kc += 128) {
        __syncthreads();
#pragma unroll
        for (int p = 0; p < 4; ++p) {
            union { bf16x8 v; uint32_t u[4]; } a0, r0;
            a0.v = rA[p];
            float4 t0 = rT[2 * p], t1 = rT[2 * p + 1];
            r0.u[0] = scale_pk(a0.u[0], t0.x, t0.y);
            r0.u[1] = scale_pk(a0.u[1], t0.z, t0.w);
            r0.u[2] = scale_pk(a0.u[2], t1.x, t1.y);
            r0.u[3] = scale_pk(a0.u[3], t1.z, t1.w);
            *(bf16x8*)&T[ar][aseg + p * 8]      = r0.v;
            *(bf16x8*)&T[64 + ar][aseg + p * 8] = rB[p];
        }
        __syncthreads();
        if (kc + 128 < K3F) {            // prefetch next k-chunk; hides under MFMA
#pragma unroll
            for (int p = 0; p < 4; ++p) {
                rA[p] = *(const bf16x8*)(srcA + kc + 128 + p * 8);
                rB[p] = *(const bf16x8*)(srcB + kc + 128 + p * 8);
                rT[2 * p]     = *(const float4*)(srcT + kc + 128 + p * 8);
                rT[2 * p + 1] = *(const float4*)(srcT + kc + 132 + p * 8);
            }
        }
#pragma unroll
        for (int kh = 0; kh < 4; ++kh) {
            bf16x8 af0 = *(const bf16x8*)&T[iw + m][kh * 32 + q * 8];
            bf16x8 af1 = *(const bf16x8*)&T[iw + 16 + m][kh * 32 + q * 8];
            bf16x8 bf0 = *(const bf16x8*)&T[64 + jw + m][kh * 32 + q * 8];
            bf16x8 bf1 = *(const bf16x8*)&T[64 + jw + 16 + m][kh * 32 + q * 8];
            acc[0][0] = __builtin_amdgcn_mfma_f32_16x16x32_bf16(af0, bf0, acc[0][0], 0, 0, 0);
            acc[0][1] = __builtin_amdgcn_mfma_f32_16x16x32_bf16(af0, bf1, acc[0][1], 0, 0, 0);
            acc[1][0] = __builtin_amdgcn_mfma_f32_16x16x32_bf16(af1, bf0, acc[1][0], 0, 0, 0);
            acc[1][1] = __builtin_amdgcn_mfma_f32_16x16x32_bf16(af1, bf1, acc[1][1], 0, 0, 0);
        }
    }
    float bias = (c < 6) ? tb[c] : sb[0];
#pragma unroll
    for (int a = 0; a < 2; ++a)
#pragma unroll
        for (int n = 0; n < 2; ++n)
#pragma unroll
            for (int rg = 0; rg < 4; ++rg) {
                int i = i0 + iw + a * 16 + q * 4 + rg;
                int j = j0 + jw + n * 16 + m;
                float v = acc[a][n][rg] + bias;
                if (c < 6) dout[((size_t)(b * 256 + i) * 256 + j) * 6 + c] = v;
                else       dout[SCOFF + (size_t)(b * 256 + i) * 256 + j] = v;
            }
}

extern "C" void kernel_launch(void* const* d_in, const int* in_sizes, int n_in,
                              void* d_out, int out_size, void* d_ws, size_t ws_size,
                              hipStream_t stream) {
    const int*   ids   = (const int*)d_in[0];
    const float* table = (const float*)d_in[1];
    const float* w2 = (const float*)d_in[2];
    const float* b2 = (const float*)d_in[3];
    const float* w3 = (const float*)d_in[4];
    const float* b3 = (const float*)d_in[5];
    const float* w4 = (const float*)d_in[6];
    const float* b4 = (const float*)d_in[7];
    const float* tw = (const float*)d_in[8];
    const float* tb = (const float*)d_in[9];
    const float* sw = (const float*)d_in[10];
    const float* sb = (const float*)d_in[11];
    float* dout = (float*)d_out;

    uint8_t* wsb = (uint8_t*)d_ws;
    uint16_t* VB   = (uint16_t*)(wsb + 0);           // 1,572,864 B
    uint16_t* embB = (uint16_t*)(wsb + 1572864);     //   557,056 B
    uint16_t* Wt2  = (uint16_t*)(wsb + 2129920);     //   262,144 B
    uint16_t* Wt3  = (uint16_t*)(wsb + 2392064);     //   393,216 B
    uint16_t* Wt4  = (uint16_t*)(wsb + 2785280);     //   524,288 B -> 3,309,568 total

    hipLaunchKernelGGL(k_prep,   dim3(804), dim3(256), 0, stream,
                       ids, table, w2, w3, w4, embB, Wt2, Wt3, Wt4);
    hipLaunchKernelGGL(k_convg,  dim3(768), dim3(256), 0, stream,
                       Wt2, Wt3, Wt4, b2, b3, b4, embB, VB);
    hipLaunchKernelGGL(k_pairc3, dim3(448), dim3(256), 0, stream,
                       VB, tw, sw, tb, sb, dout);
}

// Round 4
// 106.400 us; speedup vs baseline: 1.0866x; 1.0866x over previous
//
#include <hip/hip_runtime.h>
#include <stdint.h>

#define LSEQ 256
#define EMB  256
#define K3F  768
#define SCOFF (4 * 256 * 256 * 6)

typedef short bf16x8 __attribute__((ext_vector_type(8)));
typedef float f32x4  __attribute__((ext_vector_type(4)));

__device__ __forceinline__ uint16_t f2bf(float x) {
    union { float f; uint32_t u; } c; c.f = x;
    uint32_t r = c.u + 0x7fffu + ((c.u >> 16) & 1u);
    return (uint16_t)(r >> 16);
}

// scale a packed pair of bf16 (in one u32) by two f32 weights, repack bf16
__device__ __forceinline__ uint32_t scale_pk(uint32_t u, float t0, float t1) {
    union { uint32_t u; float f; } lo, hi;
    lo.u = u << 16;
    hi.u = u & 0xffff0000u;
    float a = lo.f * t0;
    float b = hi.f * t1;
    return (uint32_t)f2bf(a) | ((uint32_t)f2bf(b) << 16);
}

// ---------- prep: gather->embB bf16 (rows 4+l, zero halo), wprep->Wt[t][c][i] bf16
// grid 804 = 32 gather + 4 pad + 768 wprep (one thread per (c,i), K loads/stores)
__global__ __launch_bounds__(256) void k_prep(const int* __restrict__ ids,
                                              const float* __restrict__ table,
                                              const float* __restrict__ w2,
                                              const float* __restrict__ w3,
                                              const float* __restrict__ w4,
                                              uint16_t* __restrict__ embB,
                                              uint16_t* __restrict__ Wt2,
                                              uint16_t* __restrict__ Wt3,
                                              uint16_t* __restrict__ Wt4) {
    int blk = blockIdx.x, tid = threadIdx.x;
    if (blk < 32) {                       // gather: 4b x 8 l-chunks of 32
        int b = blk >> 3, l0 = (blk & 7) << 5;
        int r = tid >> 3, p = tid & 7;
        int id = ids[(b << 8) + l0 + r];
        const float* src = table + (size_t)id * EMB + p * 32;
        uint16_t* dst = embB + (size_t)(b * 272 + 4 + l0 + r) * 256 + p * 32;
#pragma unroll
        for (int s = 0; s < 8; ++s) {
            float4 v = *(const float4*)(src + 4 * s);
            uint32_t lo = f2bf(v.x) | ((uint32_t)f2bf(v.y) << 16);
            uint32_t hi = f2bf(v.z) | ((uint32_t)f2bf(v.w) << 16);
            *(uint2*)(dst + 4 * s) = make_uint2(lo, hi);
        }
    } else if (blk < 36) {                // zero pad rows 0..3, 260..271
        int b = blk - 32;
        int ri = tid >> 4;
        int row = ri < 4 ? ri : 256 + ri;
        int off = (tid & 15) * 16;
        uint16_t* dst = embB + (size_t)(b * 272 + row) * 256 + off;
        *(uint4*)dst = make_uint4(0, 0, 0, 0);
        *(uint4*)(dst + 8) = make_uint4(0, 0, 0, 0);
    } else {                              // wprep: thread = (c,i), 65536 per group
        int n = (blk - 36) * 256 + tid;
        if (n < 65536) {
            int c = n >> 8, i = n & 255;
            float2 v = *(const float2*)(w2 + (c << 9) + (i << 1));
            Wt2[c * 256 + i]         = f2bf(v.x);
            Wt2[65536 + c * 256 + i] = f2bf(v.y);
        } else if (n < 131072) {
            int m = n - 65536;
            int c = m >> 8, i = m & 255;
            const float* s = w3 + c * 768 + i * 3;
#pragma unroll
            for (int t = 0; t < 3; ++t)
                Wt3[t * 65536 + c * 256 + i] = f2bf(s[t]);
        } else {
            int m = n - 131072;
            int c = m >> 8, i = m & 255;
            float4 v = *(const float4*)(w4 + (c << 10) + (i << 2));
            Wt4[c * 256 + i]              = f2bf(v.x);
            Wt4[65536 + c * 256 + i]      = f2bf(v.y);
            Wt4[2 * 65536 + c * 256 + i]  = f2bf(v.z);
            Wt4[3 * 65536 + c * 256 + i]  = f2bf(v.w);
        }
    }
}

// ---------- conv as MFMA GEMM, 32c x 32l tiles, i-chunk 128 (2 phases, 4 barriers)
template <int K, int PAD>
__device__ __forceinline__ void convg_body(const uint16_t* __restrict__ Wt,
                                           const float* __restrict__ bias,
                                           const uint16_t* __restrict__ embB,
                                           uint16_t* __restrict__ VB,
                                           int b, int c0, int l0, int gbase,
                                           uint16_t (*As)[32][136], uint16_t (*Bs)[136]) {
    const int tid = threadIdx.x;
    const int lane = tid & 63, wave = tid >> 6;
    const int ms = wave >> 1, ns = wave & 1;
    const int m = lane & 15, q = lane >> 4;
    const int ar = tid >> 3, aseg = (tid & 7) * 16;   // 32 rows, 8 thr/row, 16 halfs

    const uint16_t* wsrc  = Wt + (size_t)(c0 + ar) * 256 + aseg;                       // +t*65536 + i0
    const uint16_t* bsrc  = embB + (size_t)(b * 272 + 3 + l0 + ar) * 256 + aseg;       // +i0
    const int r2 = 32 + (tid >> 3);
    const uint16_t* bsrc2 = embB + (size_t)(b * 272 + 3 + l0 + r2) * 256 + aseg;       // tid<32 only

    bf16x8 ra[K][2], rb[2], rb2[2];
#pragma unroll
    for (int t = 0; t < K; ++t) {
        ra[t][0] = *(const bf16x8*)(wsrc + t * 65536);
        ra[t][1] = *(const bf16x8*)(wsrc + t * 65536 + 8);
    }
    rb[0] = *(const bf16x8*)bsrc;
    rb[1] = *(const bf16x8*)(bsrc + 8);
    if (tid < 32) {
        rb2[0] = *(const bf16x8*)bsrc2;
        rb2[1] = *(const bf16x8*)(bsrc2 + 8);
    }

    f32x4 acc;
#pragma unroll
    for (int z = 0; z < 4; ++z) acc[z] = 0.f;

#pragma unroll
    for (int i0 = 0; i0 < EMB; i0 += 128) {
        __syncthreads();
#pragma unroll
        for (int t = 0; t < K; ++t) {
            *(bf16x8*)&As[t][ar][aseg]     = ra[t][0];
            *(bf16x8*)&As[t][ar][aseg + 8] = ra[t][1];
        }
        *(bf16x8*)&Bs[ar][aseg]     = rb[0];
        *(bf16x8*)&Bs[ar][aseg + 8] = rb[1];
        if (tid < 32) {
            *(bf16x8*)&Bs[r2][aseg]     = rb2[0];
            *(bf16x8*)&Bs[r2][aseg + 8] = rb2[1];
        }
        __syncthreads();
        if (i0 + 128 < EMB) {           // prefetch next i-chunk; latency hides under MFMA
#pragma unroll
            for (int t = 0; t < K; ++t) {
                ra[t][0] = *(const bf16x8*)(wsrc + t * 65536 + i0 + 128);
                ra[t][1] = *(const bf16x8*)(wsrc + t * 65536 + i0 + 136);
            }
            rb[0] = *(const bf16x8*)(bsrc + i0 + 128);
            rb[1] = *(const bf16x8*)(bsrc + i0 + 136);
            if (tid < 32) {
                rb2[0] = *(const bf16x8*)(bsrc2 + i0 + 128);
                rb2[1] = *(const bf16x8*)(bsrc2 + i0 + 136);
            }
        }
#pragma unroll
        for (int t = 0; t < K; ++t) {
#pragma unroll
            for (int kh = 0; kh < 128; kh += 32) {
                bf16x8 afr = *(const bf16x8*)&As[t][ms * 16 + m][kh + q * 8];
                bf16x8 bfr = *(const bf16x8*)&Bs[ns * 16 + m + t - PAD + 1][kh + q * 8];
                acc = __builtin_amdgcn_mfma_f32_16x16x32_bf16(afr, bfr, acc, 0, 0, 0);
            }
        }
    }
    __syncthreads();
    float (*Cs)[36] = (float(*)[36])As;   // 4,608 B reuse
#pragma unroll
    for (int rg = 0; rg < 4; ++rg)
        Cs[ms * 16 + q * 4 + rg][ns * 16 + m] = acc[rg];
    __syncthreads();
    const int l = tid >> 3, cs = (tid & 7) * 4;
    const float4 bv = *(const float4*)(bias + c0 + cs);
    union { uint16_t h[4]; uint32_t d[2]; } pk;
    pk.h[0] = f2bf(Cs[cs + 0][l] + bv.x);
    pk.h[1] = f2bf(Cs[cs + 1][l] + bv.y);
    pk.h[2] = f2bf(Cs[cs + 2][l] + bv.z);
    pk.h[3] = f2bf(Cs[cs + 3][l] + bv.w);
    uint16_t* vdst = VB + (size_t)(b * 256 + l0 + l) * K3F + gbase + c0 + cs;
    *(uint2*)vdst = make_uint2(pk.d[0], pk.d[1]);
}

__global__ __launch_bounds__(256, 3) void k_convg(const uint16_t* __restrict__ Wt2,
                                                  const uint16_t* __restrict__ Wt3,
                                                  const uint16_t* __restrict__ Wt4,
                                                  const float* __restrict__ b2,
                                                  const float* __restrict__ b3,
                                                  const float* __restrict__ b4,
                                                  const uint16_t* __restrict__ embB,
                                                  uint16_t* __restrict__ VB) {
    __shared__ __align__(16) uint16_t As[4][32][136];   // 34.8 KB
    __shared__ __align__(16) uint16_t Bs[36][136];      //  9.8 KB -> 44.6 KB, 3 blocks/CU
    int blk = blockIdx.x;                 // 768 = 4b * 3g * 8c0 * 8l0 = exactly 3 blocks/CU
    int b = blk & 3, rest = blk >> 2;
    int g = rest >> 6, rr = rest & 63;
    int c0 = (rr >> 3) * 32, l0 = (rr & 7) * 32;
    if (g == 0)      convg_body<2, 0>(Wt2, b2, embB, VB, b, c0, l0, 0,   As, Bs);
    else if (g == 1) convg_body<3, 1>(Wt3, b3, embB, VB, b, c0, l0, 256, As, Bs);
    else             convg_body<4, 1>(Wt4, b4, embB, VB, b, c0, l0, 512, As, Bs);
}

// ---------- pair GEMM: block = (b, c, i-tile 32, j-pair 64): 896 blocks (R1 proven form)
__global__ __launch_bounds__(256, 4) void k_pairc2(const uint16_t* __restrict__ VB,
                                                   const float* __restrict__ tw,
                                                   const float* __restrict__ sw,
                                                   const float* __restrict__ tb,
                                                   const float* __restrict__ sb,
                                                   float* __restrict__ dout) {
    __shared__ __align__(16) uint16_t T[96][136]; // rows 0..31 = scaled A(i), 32..95 = VB(j0..j0+63)
    __shared__ __align__(16) float twL[768];
    int blk = blockIdx.x;
    int b = blk & 3, it = (blk >> 2) & 7;
    int rest = blk >> 5;
    int c = rest % 7, jp = rest / 7;
    int i0 = it * 32, j0 = jp * 64;
    int tid = threadIdx.x;

    const float* srow = (c < 6) ? (tw + c * K3F) : sw;
    twL[tid]       = srow[tid];
    twL[256 + tid] = srow[256 + tid];
    twL[512 + tid] = srow[512 + tid];

    int lane = tid & 63, wave = tid >> 6;
    int iw = wave >> 1, jw = wave & 1;
    int m = lane & 15, q = lane >> 4;
    int rr = tid >> 3, seg = (tid & 7) * 16;   // 32 rows/pass, 8 thr/row, 16 halfs

    const uint16_t* srcI  = VB + (size_t)(b * 256 + i0 + rr) * K3F + seg;
    const uint16_t* srcJ0 = VB + (size_t)(b * 256 + j0 + rr) * K3F + seg;
    const uint16_t* srcJ1 = VB + (size_t)(b * 256 + j0 + 32 + rr) * K3F + seg;

    bf16x8 rI0, rI1, rJ00, rJ01, rJ10, rJ11;
    rI0  = *(const bf16x8*)(srcI);      rI1  = *(const bf16x8*)(srcI + 8);
    rJ00 = *(const bf16x8*)(srcJ0);     rJ01 = *(const bf16x8*)(srcJ0 + 8);
    rJ10 = *(const bf16x8*)(srcJ1);     rJ11 = *(const bf16x8*)(srcJ1 + 8);

    f32x4 acc[2];
#pragma unroll
    for (int n = 0; n < 2; ++n)
#pragma unroll
        for (int z = 0; z < 4; ++z) acc[n][z] = 0.f;

#pragma unroll
    for (int kc = 0; kc < K3F; kc += 128) {
        __syncthreads();
        {   // scaled A rows: T[rr] = bf16( VB_i * tw_c )
            const float* twp = twL + kc + seg;
            float4 t0 = *(const float4*)(twp + 0);
            float4 t1 = *(const float4*)(twp + 4);
            float4 t2 = *(const float4*)(twp + 8);
            float4 t3 = *(const float4*)(twp + 12);
            union { bf16x8 v; uint32_t u[4]; } a0, a1, r0, r1;
            a0.v = rI0; a1.v = rI1;
            r0.u[0] = scale_pk(a0.u[0], t0.x, t0.y);
            r0.u[1] = scale_pk(a0.u[1], t0.z, t0.w);
            r0.u[2] = scale_pk(a0.u[2], t1.x, t1.y);
            r0.u[3] = scale_pk(a0.u[3], t1.z, t1.w);
            r1.u[0] = scale_pk(a1.u[0], t2.x, t2.y);
            r1.u[1] = scale_pk(a1.u[1], t2.z, t2.w);
            r1.u[2] = scale_pk(a1.u[2], t3.x, t3.y);
            r1.u[3] = scale_pk(a1.u[3], t3.z, t3.w);
            *(bf16x8*)&T[rr][seg]     = r0.v;
            *(bf16x8*)&T[rr][seg + 8] = r1.v;
        }
        *(bf16x8*)&T[32 + rr][seg]     = rJ00;
        *(bf16x8*)&T[32 + rr][seg + 8] = rJ01;
        *(bf16x8*)&T[64 + rr][seg]     = rJ10;
        *(bf16x8*)&T[64 + rr][seg + 8] = rJ11;
        __syncthreads();
        if (kc + 128 < K3F) {           // prefetch next k-chunk; hides under MFMA
            rI0  = *(const bf16x8*)(srcI + kc + 128);
            rI1  = *(const bf16x8*)(srcI + kc + 136);
            rJ00 = *(const bf16x8*)(srcJ0 + kc + 128);
            rJ01 = *(const bf16x8*)(srcJ0 + kc + 136);
            rJ10 = *(const bf16x8*)(srcJ1 + kc + 128);
            rJ11 = *(const bf16x8*)(srcJ1 + kc + 136);
        }
#pragma unroll
        for (int kh = 0; kh < 4; ++kh) {
            bf16x8 afr  = *(const bf16x8*)&T[iw * 16 + m][kh * 32 + q * 8];
            bf16x8 bfr0 = *(const bf16x8*)&T[32 + jw * 32 + m][kh * 32 + q * 8];
            bf16x8 bfr1 = *(const bf16x8*)&T[32 + jw * 32 + 16 + m][kh * 32 + q * 8];
            acc[0] = __builtin_amdgcn_mfma_f32_16x16x32_bf16(afr, bfr0, acc[0], 0, 0, 0);
            acc[1] = __builtin_amdgcn_mfma_f32_16x16x32_bf16(afr, bfr1, acc[1], 0, 0, 0);
        }
    }
    float bias = (c < 6) ? tb[c] : sb[0];
#pragma unroll
    for (int n = 0; n < 2; ++n)
#pragma unroll
        for (int rg = 0; rg < 4; ++rg) {
            int i = i0 + iw * 16 + q * 4 + rg;
            int j = j0 + jw * 32 + n * 16 + m;
            float v = acc[n][rg] + bias;
            if (c < 6) dout[((size_t)(b * 256 + i) * 256 + j) * 6 + c] = v;
            else       dout[SCOFF + (size_t)(b * 256 + i) * 256 + j] = v;
        }
}

extern "C" void kernel_launch(void* const* d_in, const int* in_sizes, int n_in,
                              void* d_out, int out_size, void* d_ws, size_t ws_size,
                              hipStream_t stream) {
    const int*   ids   = (const int*)d_in[0];
    const float* table = (const float*)d_in[1];
    const float* w2 = (const float*)d_in[2];
    const float* b2 = (const float*)d_in[3];
    const float* w3 = (const float*)d_in[4];
    const float* b3 = (const float*)d_in[5];
    const float* w4 = (const float*)d_in[6];
    const float* b4 = (const float*)d_in[7];
    const float* tw = (const float*)d_in[8];
    const float* tb = (const float*)d_in[9];
    const float* sw = (const float*)d_in[10];
    const float* sb = (const float*)d_in[11];
    float* dout = (float*)d_out;

    uint8_t* wsb = (uint8_t*)d_ws;
    uint16_t* VB   = (uint16_t*)(wsb + 0);           // 1,572,864 B
    uint16_t* embB = (uint16_t*)(wsb + 1572864);     //   557,056 B
    uint16_t* Wt2  = (uint16_t*)(wsb + 2129920);     //   262,144 B
    uint16_t* Wt3  = (uint16_t*)(wsb + 2392064);     //   393,216 B
    uint16_t* Wt4  = (uint16_t*)(wsb + 2785280);     //   524,288 B -> 3,309,568 total

    hipLaunchKernelGGL(k_prep,   dim3(804), dim3(256), 0, stream,
                       ids, table, w2, w3, w4, embB, Wt2, Wt3, Wt4);
    hipLaunchKernelGGL(k_convg,  dim3(768), dim3(256), 0, stream,
                       Wt2, Wt3, Wt4, b2, b3, b4, embB, VB);
    hipLaunchKernelGGL(k_pairc2, dim3(896), dim3(256), 0, stream,
                       VB, tw, sw, tb, sb, dout);
}